// Round 5
// baseline (817.796 us; speedup 1.0000x reference)
//
#include <hip/hip_runtime.h>
#include <hip/hip_bf16.h>
#include <cstdint>
#include <cstddef>

// ---------------------------------------------------------------------------
// HopfieldModel: z = x@W_enc; 4x { q <- softmax(2 q K^T) K } per network;
// out = log_softmax(relu(concat q) @ W_lin + b_lin)
//
// scan (fp16 MFMA, single pass, per-wave private online threshold): emits
// packed (key<<16 | fp16 score) for s >= running_wave_max - EMIT_MARGIN.
// Superset property: wave_max <= global_max, so every key within EMIT_MARGIN
// of the global max is emitted.  refine: global candidate max from STORED
// fp16 scores (no gather), filter to ~10 survivors within SEL_MARGIN, exact
// fp32 re-score of survivors only, exact softmax+PV.  Dropped softmax mass
// <= O(10)*e^-9.4 ~ 3e-4 -> far below the 0.11 output threshold.
// ---------------------------------------------------------------------------

#define NNET 4
#define NQ   256
#define EDIM 128
#define NKEY 32768
#define ESTR 129              // embeddings row stride (col 128 dropped)
#define QT   64               // q rows per scan block
#define NCHUNK 16
#define KPC  (NKEY/NCHUNK)    // 2048 keys per chunk
#define SCAN_WAVES 8
#define KPW  (KPC/SCAN_WAVES) // 256 keys per wave
#define SLICES (KPW/16)       // 16 slices of 16 keys
#define GRP 4                 // slices per threshold-update group
#define MAXCAP 2048
#define EMIT_MARGIN 10.0f
#define SEL_MARGIN  9.5f

typedef _Float16 half8 __attribute__((ext_vector_type(8)));
typedef float f32x4v __attribute__((ext_vector_type(4)));

__device__ __forceinline__ float dec16(unsigned v) {
  _Float16 h = __builtin_bit_cast(_Float16, (unsigned short)(v & 0xFFFFu));
  return (float)h;
}
__device__ __forceinline__ unsigned pack16(int key, float s) {
  unsigned short hb = __builtin_bit_cast(unsigned short, (_Float16)s);
  return ((unsigned)key << 16) | (unsigned)hb;
}

// --------------------------- encoder: z = x@We + be -------------------------
__global__ __launch_bounds__(128)
void enc_kernel(const float* __restrict__ x, const float* __restrict__ We,
                const float* __restrict__ be, float* __restrict__ q0,
                int* __restrict__ cnt) {
  const int b = blockIdx.x, tid = threadIdx.x;
  __shared__ float xs[784];
  for (int i = tid; i < 784; i += 128) xs[i] = x[b * 784 + i];
  __syncthreads();
  float acc = be[tid];
  for (int i = 0; i < 784; ++i) acc += xs[i] * We[i * EDIM + tid];
#pragma unroll
  for (int n = 0; n < NNET; ++n) q0[((size_t)n * NQ + b) * EDIM + tid] = acc;
  if (b == 0)
    for (int i = tid; i < NNET * NQ; i += 128) cnt[i] = 0;
}

// ------------------- keyprep: embeddings f32 -> fp16 (drop col 128) --------
// 4 elements per thread, vector half4 stores.
typedef _Float16 half4v __attribute__((ext_vector_type(4)));
__global__ __launch_bounds__(256)
void keyprep_kernel(const float* __restrict__ emb, _Float16* __restrict__ kh) {
  const size_t quads = (size_t)NNET * NKEY * EDIM / 4;
  for (size_t i4 = (size_t)blockIdx.x * 256 + threadIdx.x; i4 < quads;
       i4 += (size_t)gridDim.x * 256) {
    const size_t row = i4 >> 5;
    const int col = (int)(i4 & 31) * 4;
    const float* src = emb + row * ESTR + col;
    half4v h;
#pragma unroll
    for (int j = 0; j < 4; ++j) h[j] = (_Float16)src[j];
    *(half4v*)(kh + i4 * 4) = h;
  }
}

// ------------------------------- scan --------------------------------------
// grid (64, 4): x = net*16+chunk, y = q-tile.  512 threads = 8 waves, each
// wave owns 256 keys.  Pure per-wave streaming: no LDS, no barriers.
template <bool F16K>
__global__ __launch_bounds__(SCAN_WAVES * 64, 2)
void scan_kernel(const float* __restrict__ qcur, const float* __restrict__ emb,
                 const _Float16* __restrict__ keysh, int* __restrict__ cnt,
                 unsigned* __restrict__ cand, int cap) {
  const int nc = blockIdx.x;
  const int net = nc >> 4, chunk = nc & 15;
  const int qt = blockIdx.y;
  const int tid = threadIdx.x;
  const int lane = tid & 63, w = tid >> 6;
  const int g = lane >> 4, ln = lane & 15;

  // Q A-fragments (16x16x32: lane holds row m=lane&15, k = 8*(lane>>4)+j),
  // beta=2 folded into q.
  half8 aq[4][4];
  {
    const float* qb = qcur + ((size_t)net * NQ + qt * QT) * EDIM;
#pragma unroll
    for (int s = 0; s < 4; ++s)
#pragma unroll
      for (int f = 0; f < 4; ++f) {
        const float* p = qb + (s * 16 + ln) * EDIM + f * 32 + g * 8;
        half8 h;
#pragma unroll
        for (int j = 0; j < 8; ++j) h[j] = (_Float16)(2.0f * p[j]);
        aq[s][f] = h;
      }
  }

  const int key0 = chunk * KPC + w * KPW;

  auto loadB = [&](int sl, half8 bk[4]) {
    const size_t keyrow = (size_t)net * NKEY + key0 + sl * 16 + ln;
    if constexpr (F16K) {
      const _Float16* kp = keysh + keyrow * EDIM + g * 8;
#pragma unroll
      for (int f = 0; f < 4; ++f) bk[f] = *(const half8*)(kp + f * 32);
    } else {
      const float* kp = emb + keyrow * ESTR + g * 8;
#pragma unroll
      for (int f = 0; f < 4; ++f) {
        half8 h;
#pragma unroll
        for (int j = 0; j < 8; ++j) h[j] = (_Float16)kp[f * 32 + j];
        bk[f] = h;
      }
    }
  };

  // private running per-row max (rows: i = s*4+r -> query row s*16+g*4+r)
  float rowmax[16];
#pragma unroll
  for (int i = 0; i < 16; ++i) rowmax[i] = -3.4e38f;
  int* mycnt = cnt + net * NQ;

  for (int gi = 0; gi < SLICES; gi += GRP) {
    f32x4v acc[GRP][4];
    // compute GRP slices, keeping accumulators
#pragma unroll
    for (int u = 0; u < GRP; ++u) {
      half8 bk[4];
      loadB(gi + u, bk);
#pragma unroll
      for (int s = 0; s < 4; ++s) acc[u][s] = f32x4v{0.f, 0.f, 0.f, 0.f};
#pragma unroll
      for (int f = 0; f < 4; ++f)
#pragma unroll
        for (int s = 0; s < 4; ++s)
          acc[u][s] = __builtin_amdgcn_mfma_f32_16x16x32_f16(aq[s][f], bk[f], acc[u][s], 0, 0, 0);
#pragma unroll
      for (int s = 0; s < 4; ++s)
#pragma unroll
        for (int r = 0; r < 4; ++r)
          rowmax[s * 4 + r] = fmaxf(rowmax[s * 4 + r], acc[u][s][r]);
    }
    // cross-lane max over the 16 key-lanes (bits 0-3); g bits untouched
#pragma unroll
    for (int d = 1; d < 16; d <<= 1)
#pragma unroll
      for (int i = 0; i < 16; ++i)
        rowmax[i] = fmaxf(rowmax[i], __shfl_xor(rowmax[i], d, 64));
    // emit retained slices against the (monotone, <= global-max) threshold
#pragma unroll
    for (int u = 0; u < GRP; ++u) {
      const int keyg = key0 + (gi + u) * 16 + ln;
#pragma unroll
      for (int s = 0; s < 4; ++s)
#pragma unroll
        for (int r = 0; r < 4; ++r)
          if (acc[u][s][r] >= rowmax[s * 4 + r] - EMIT_MARGIN) {
            int q = qt * QT + s * 16 + g * 4 + r;
            int slot = atomicAdd(&mycnt[q], 1);
            if (slot < cap)
              cand[((size_t)net * NQ + q) * cap + slot] = pack16(keyg, acc[u][s][r]);
          }
    }
  }
}

// ------------------------------- refine ------------------------------------
// one block (256 thr) per (query, net).  Global candidate max from STORED
// fp16 scores; filter to survivors (>= max - SEL_MARGIN); exact fp32 scores
// for survivors only; exact softmax + PV.  Deterministic compaction order.
__global__ __launch_bounds__(256)
void refine_kernel(const float* __restrict__ qcur, const float* __restrict__ emb,
                   int* __restrict__ cnt, const unsigned* __restrict__ cand,
                   float* __restrict__ qnext, int cap) {
  const int q = blockIdx.x, net = blockIdx.y;
  const int tid = threadIdx.x, lane = tid & 63, w = tid >> 6;
  const int slot = net * NQ + q;
  __shared__ float qv[EDIM];
  __shared__ float osh[EDIM];
  __shared__ unsigned pr[MAXCAP];
  __shared__ unsigned surv[4][64];
  __shared__ unsigned list[256];
  __shared__ float exsc[256];
  __shared__ int scnt[4];
  __shared__ float red[8];

  const int ntot = cnt[slot];
  const int n = ntot < cap ? ntot : cap;
  if (tid < EDIM) qv[tid] = 2.0f * qcur[(size_t)slot * EDIM + tid];
  for (int j = tid; j < n; j += 256) pr[j] = cand[(size_t)slot * cap + j];
  __syncthreads();

  if (ntot <= cap) {
    // ---- global max over stored fp16 scores (no memory gather) ----
    float mx = -3.4e38f;
    for (int j = tid; j < n; j += 256) mx = fmaxf(mx, dec16(pr[j]));
#pragma unroll
    for (int d = 32; d; d >>= 1) mx = fmaxf(mx, __shfl_xor(mx, d, 64));
    if (lane == 0) red[w] = mx;
    __syncthreads();
    mx = fmaxf(fmaxf(red[0], red[1]), fmaxf(red[2], red[3]));
    const float th = mx - SEL_MARGIN;

    // ---- deterministic wave-striped compaction of survivors ----
    const int n4 = (n + 3) >> 2;
    const int lo = w * n4;
    const int hi = min(lo + n4, n);
    int c = 0;  // wave-uniform running count
    for (int base = lo; base < hi; base += 64) {
      const int j = base + lane;
      const bool p = (j < hi) && (dec16(pr[j]) >= th);
      const unsigned long long mb = __ballot(p);
      const int pos = c + __popcll(mb & ((1ull << lane) - 1));
      if (p && pos < 64) surv[w][pos] = pr[j];
      c += (int)__popcll(mb);
    }
    if (lane == 0) scnt[w] = c < 64 ? c : 64;
    __syncthreads();
    const int o1 = scnt[0], o2 = o1 + scnt[1], o3 = o2 + scnt[2];
    const int m = o3 + scnt[3];
    const int offw = (w == 0) ? 0 : (w == 1 ? o1 : (w == 2 ? o2 : o3));
    if (lane < scnt[w]) list[offw + lane] = surv[w][lane];
    __syncthreads();

    // ---- exact fp32 scores for the m survivors ----
    for (int j = w; j < m; j += 4) {
      const int ki = (int)(list[j] >> 16);
      const float* kr = emb + ((size_t)net * NKEY + ki) * ESTR;
      float p2 = qv[2 * lane] * kr[2 * lane] + qv[2 * lane + 1] * kr[2 * lane + 1];
#pragma unroll
      for (int d = 32; d; d >>= 1) p2 += __shfl_xor(p2, d, 64);
      if (lane == 0) exsc[j] = p2;
    }
    __syncthreads();
    if (w == 0) {
      float em = -3.4e38f;
      for (int j = lane; j < m; j += 64) em = fmaxf(em, exsc[j]);
#pragma unroll
      for (int d = 32; d; d >>= 1) em = fmaxf(em, __shfl_xor(em, d, 64));
      if (lane == 0) red[4] = em;
    }
    __syncthreads();
    const float em = red[4];
    for (int j = tid; j < m; j += 256) exsc[j] = expf(exsc[j] - em);
    __syncthreads();
    if (w == 0) {
      float l = 0.f;
      for (int j = lane; j < m; j += 64) l += exsc[j];
#pragma unroll
      for (int d = 32; d; d >>= 1) l += __shfl_xor(l, d, 64);
      if (lane == 0) red[5] = l;
    }
    __syncthreads();
    // ---- exact PV over survivors ----
    const float inv = 1.0f / red[5];
    const int e = tid & 127, hf = tid >> 7;
    float acc = 0.f;
    for (int j = hf; j < m; j += 2)
      acc += exsc[j] * emb[((size_t)net * NKEY + (int)(list[j] >> 16)) * ESTR + e];
    if (hf) osh[e] = acc;
    __syncthreads();
    if (!hf) qnext[(size_t)slot * EDIM + e] = (acc + osh[e]) * inv;
  } else {
    // ---- exact full-scan fallback (overflow only; never expected) ----
    float mm = -3.4e38f;
    for (int j = w; j < NKEY; j += 4) {
      const float* kr = emb + ((size_t)net * NKEY + j) * ESTR;
      float p = qv[2 * lane] * kr[2 * lane] + qv[2 * lane + 1] * kr[2 * lane + 1];
#pragma unroll
      for (int d = 32; d; d >>= 1) p += __shfl_xor(p, d, 64);
      mm = fmaxf(mm, p);
    }
    if (lane == 0) red[w] = mm;
    __syncthreads();
    mm = fmaxf(fmaxf(red[0], red[1]), fmaxf(red[2], red[3]));
    if (tid < EDIM) osh[tid] = 0.f;
    if (tid == 0) red[4] = 0.f;
    __syncthreads();
    float lpart = 0.f;
    for (int j = w; j < NKEY; j += 4) {
      const float* kr = emb + ((size_t)net * NKEY + j) * ESTR;
      float p = qv[2 * lane] * kr[2 * lane] + qv[2 * lane + 1] * kr[2 * lane + 1];
#pragma unroll
      for (int d = 32; d; d >>= 1) p += __shfl_xor(p, d, 64);
      float ee = expf(p - mm);
      if (lane == 0) lpart += ee;
      atomicAdd(&osh[2 * lane], ee * kr[2 * lane]);
      atomicAdd(&osh[2 * lane + 1], ee * kr[2 * lane + 1]);
    }
    if (lane == 0) atomicAdd(&red[4], lpart);
    __syncthreads();
    if (tid < EDIM) qnext[(size_t)slot * EDIM + tid] = osh[tid] / red[4];
  }
  __syncthreads();
  if (tid == 0) cnt[slot] = 0;  // ready for next step's scan
}

// ------------------------------- head --------------------------------------
__global__ __launch_bounds__(64)
void head_kernel(const float* __restrict__ qf, const float* __restrict__ Wl,
                 const float* __restrict__ bl, float* __restrict__ out) {
  const int b = blockIdx.x, lane = threadIdx.x;
  float acc[10];
#pragma unroll
  for (int c = 0; c < 10; ++c) acc[c] = 0.f;
  for (int t = lane; t < NNET * EDIM; t += 64) {
    float z = qf[((size_t)(t >> 7) * NQ + b) * EDIM + (t & 127)];
    z = fmaxf(z, 0.f);
    const float* wr = Wl + t * 10;
#pragma unroll
    for (int c = 0; c < 10; ++c) acc[c] += z * wr[c];
  }
#pragma unroll
  for (int d = 32; d; d >>= 1)
#pragma unroll
    for (int c = 0; c < 10; ++c) acc[c] += __shfl_xor(acc[c], d, 64);
  if (lane == 0) {
    float lg[10], mxv = -3.4e38f;
#pragma unroll
    for (int c = 0; c < 10; ++c) {
      lg[c] = acc[c] + bl[c];
      mxv = fmaxf(mxv, lg[c]);
    }
    float s = 0.f;
#pragma unroll
    for (int c = 0; c < 10; ++c) s += expf(lg[c] - mxv);
    float lse = mxv + logf(s);
#pragma unroll
    for (int c = 0; c < 10; ++c) out[b * 10 + c] = lg[c] - lse;
  }
}

// ------------------------------- launch ------------------------------------
extern "C" void kernel_launch(void* const* d_in, const int* in_sizes, int n_in,
                              void* d_out, int out_size, void* d_ws, size_t ws_size,
                              hipStream_t stream) {
  (void)in_sizes; (void)n_in; (void)out_size;
  const float* x   = (const float*)d_in[0];
  const float* emb = (const float*)d_in[1];
  const float* We  = (const float*)d_in[2];
  const float* be  = (const float*)d_in[3];
  const float* Wl  = (const float*)d_in[4];
  const float* bl  = (const float*)d_in[5];
  float* out = (float*)d_out;

  char* p = (char*)d_ws;
  float* q0 = (float*)p; p += (size_t)NNET * NQ * EDIM * 4;
  float* q1 = (float*)p; p += (size_t)NNET * NQ * EDIM * 4;
  int* cnt  = (int*)p;   p += (size_t)NNET * NQ * sizeof(int);
  size_t base = (size_t)(p - (char*)d_ws);
  int cap = MAXCAP;
  while (cap > 64 && base + (size_t)NNET * NQ * cap * 4 > ws_size) cap >>= 1;
  unsigned* cand = (unsigned*)p; p += (size_t)NNET * NQ * cap * 4;
  _Float16* kh = (_Float16*)p;
  const bool f16k =
      ((size_t)(p - (char*)d_ws) + (size_t)NNET * NKEY * EDIM * 2) <= ws_size;

  enc_kernel<<<dim3(NQ), dim3(128), 0, stream>>>(x, We, be, q0, cnt);
  if (f16k)
    keyprep_kernel<<<dim3(4096), dim3(256), 0, stream>>>(emb, kh);

  float* qa = q0;
  float* qb = q1;
  for (int step = 0; step < 4; ++step) {
    if (f16k)
      scan_kernel<true><<<dim3(NNET * NCHUNK, NQ / QT), dim3(SCAN_WAVES * 64), 0, stream>>>(
          qa, emb, kh, cnt, cand, cap);
    else
      scan_kernel<false><<<dim3(NNET * NCHUNK, NQ / QT), dim3(SCAN_WAVES * 64), 0, stream>>>(
          qa, emb, (const _Float16*)nullptr, cnt, cand, cap);
    refine_kernel<<<dim3(NQ, NNET), dim3(256), 0, stream>>>(qa, emb, cnt, cand, qb, cap);
    float* t = qa; qa = qb; qb = t;
  }
  head_kernel<<<dim3(NQ), dim3(64), 0, stream>>>(qa, Wl, bl, out);
}

// Round 6
// 799.218 us; speedup vs baseline: 1.0232x; 1.0232x over previous
//
#include <hip/hip_runtime.h>
#include <hip/hip_bf16.h>
#include <cstdint>
#include <cstddef>

// ---------------------------------------------------------------------------
// HopfieldModel: z = x@W_enc; 4x { q <- softmax(2 q K^T) K } per network;
// out = log_softmax(relu(concat q) @ W_lin + b_lin)
//
// scan (fp16 MFMA, single pass, per-wave private online threshold): emits
// packed (key<<16 | fp16 score) for s >= running_wave_max - EMIT_MARGIN.
// Superset property: wave_max <= global_max, so every key within EMIT_MARGIN
// of the global max is emitted.  refine: global candidate max from STORED
// fp16 scores (no gather), filter to ~10 survivors within SEL_MARGIN, exact
// fp32 re-score of survivors only, exact softmax+PV.  Dropped softmax mass
// <= O(10)*e^-9.4 ~ 3e-4 -> far below the 0.11 output threshold.
//
// NOTE (round-5 lesson): do NOT put a min-waves arg in __launch_bounds__ on
// the scan kernel — it forces VGPR<=128 and spills the MFMA accumulators
// (observed: VGPR=108, 35 MB scratch writes, 204us dispatches).
// ---------------------------------------------------------------------------

#define NNET 4
#define NQ   256
#define EDIM 128
#define NKEY 32768
#define ESTR 129              // embeddings row stride (col 128 dropped)
#define QT   32               // q rows per scan block
#define NCHUNK 32
#define KPC  (NKEY/NCHUNK)    // 1024 keys per chunk
#define SCAN_WAVES 4
#define KPW  (KPC/SCAN_WAVES) // 256 keys per wave
#define SLICES (KPW/16)       // 16 slices of 16 keys
#define GRP 4                 // slices per threshold-update group
#define SROW (QT/16)          // 2 row-tiles of 16 q rows
#define MAXCAP 2048
#define EMIT_MARGIN 10.0f
#define SEL_MARGIN  9.5f

typedef _Float16 half8 __attribute__((ext_vector_type(8)));
typedef float f32x4v __attribute__((ext_vector_type(4)));

__device__ __forceinline__ float dec16(unsigned v) {
  _Float16 h = __builtin_bit_cast(_Float16, (unsigned short)(v & 0xFFFFu));
  return (float)h;
}
__device__ __forceinline__ unsigned pack16(int key, float s) {
  unsigned short hb = __builtin_bit_cast(unsigned short, (_Float16)s);
  return ((unsigned)key << 16) | (unsigned)hb;
}

// --------------------------- encoder: z = x@We + be -------------------------
__global__ __launch_bounds__(128)
void enc_kernel(const float* __restrict__ x, const float* __restrict__ We,
                const float* __restrict__ be, float* __restrict__ q0,
                int* __restrict__ cnt) {
  const int b = blockIdx.x, tid = threadIdx.x;
  __shared__ float xs[784];
  for (int i = tid; i < 784; i += 128) xs[i] = x[b * 784 + i];
  __syncthreads();
  float acc = be[tid];
  for (int i = 0; i < 784; ++i) acc += xs[i] * We[i * EDIM + tid];
#pragma unroll
  for (int n = 0; n < NNET; ++n) q0[((size_t)n * NQ + b) * EDIM + tid] = acc;
  if (b == 0)
    for (int i = tid; i < NNET * NQ; i += 128) cnt[i] = 0;
}

// ------------------- keyprep: embeddings f32 -> fp16 (drop col 128) --------
typedef _Float16 half4v __attribute__((ext_vector_type(4)));
__global__ __launch_bounds__(256)
void keyprep_kernel(const float* __restrict__ emb, _Float16* __restrict__ kh) {
  const size_t quads = (size_t)NNET * NKEY * EDIM / 4;
  for (size_t i4 = (size_t)blockIdx.x * 256 + threadIdx.x; i4 < quads;
       i4 += (size_t)gridDim.x * 256) {
    const size_t row = i4 >> 5;
    const int col = (int)(i4 & 31) * 4;
    const float* src = emb + row * ESTR + col;
    half4v h;
#pragma unroll
    for (int j = 0; j < 4; ++j) h[j] = (_Float16)src[j];
    *(half4v*)(kh + i4 * 4) = h;
  }
}

// ------------------------------- scan --------------------------------------
// grid (128, 8): x = net*32+chunk, y = q-tile (32 rows).  256 threads =
// 4 waves, each wave owns 256 keys.  Pure per-wave streaming: no LDS, no
// barriers.  Same-x blocks share an XCD (linear id mod 8 == x mod 8), so the
// 256KB key chunk is served from one XCD's L2.
template <bool F16K>
__global__ __launch_bounds__(SCAN_WAVES * 64)
void scan_kernel(const float* __restrict__ qcur, const float* __restrict__ emb,
                 const _Float16* __restrict__ keysh, int* __restrict__ cnt,
                 unsigned* __restrict__ cand, int cap) {
  const int nc = blockIdx.x;
  const int net = nc >> 5, chunk = nc & 31;
  const int qt = blockIdx.y;
  const int tid = threadIdx.x;
  const int lane = tid & 63, w = tid >> 6;
  const int g = lane >> 4, ln = lane & 15;

  // Q A-fragments (16x16x32: lane holds row m=lane&15, k = 8*(lane>>4)+j),
  // beta=2 folded into q.
  half8 aq[SROW][4];
  {
    const float* qb = qcur + ((size_t)net * NQ + qt * QT) * EDIM;
#pragma unroll
    for (int s = 0; s < SROW; ++s)
#pragma unroll
      for (int f = 0; f < 4; ++f) {
        const float* p = qb + (s * 16 + ln) * EDIM + f * 32 + g * 8;
        half8 h;
#pragma unroll
        for (int j = 0; j < 8; ++j) h[j] = (_Float16)(2.0f * p[j]);
        aq[s][f] = h;
      }
  }

  const int key0 = chunk * KPC + w * KPW;

  auto loadB = [&](int sl, half8 bk[4]) {
    const size_t keyrow = (size_t)net * NKEY + key0 + sl * 16 + ln;
    if constexpr (F16K) {
      const _Float16* kp = keysh + keyrow * EDIM + g * 8;
#pragma unroll
      for (int f = 0; f < 4; ++f) bk[f] = *(const half8*)(kp + f * 32);
    } else {
      const float* kp = emb + keyrow * ESTR + g * 8;
#pragma unroll
      for (int f = 0; f < 4; ++f) {
        half8 h;
#pragma unroll
        for (int j = 0; j < 8; ++j) h[j] = (_Float16)kp[f * 32 + j];
        bk[f] = h;
      }
    }
  };

  // private running per-row max (rows: i = s*4+r -> query row s*16+g*4+r)
  float rowmax[SROW * 4];
#pragma unroll
  for (int i = 0; i < SROW * 4; ++i) rowmax[i] = -3.4e38f;
  int* mycnt = cnt + net * NQ;

  for (int gi = 0; gi < SLICES; gi += GRP) {
    f32x4v acc[GRP][SROW];
    // compute GRP slices, keeping accumulators
#pragma unroll
    for (int u = 0; u < GRP; ++u) {
      half8 bk[4];
      loadB(gi + u, bk);
#pragma unroll
      for (int s = 0; s < SROW; ++s) acc[u][s] = f32x4v{0.f, 0.f, 0.f, 0.f};
#pragma unroll
      for (int f = 0; f < 4; ++f)
#pragma unroll
        for (int s = 0; s < SROW; ++s)
          acc[u][s] = __builtin_amdgcn_mfma_f32_16x16x32_f16(aq[s][f], bk[f], acc[u][s], 0, 0, 0);
#pragma unroll
      for (int s = 0; s < SROW; ++s)
#pragma unroll
        for (int r = 0; r < 4; ++r)
          rowmax[s * 4 + r] = fmaxf(rowmax[s * 4 + r], acc[u][s][r]);
    }
    // cross-lane max over the 16 key-lanes (bits 0-3); g bits untouched
#pragma unroll
    for (int d = 1; d < 16; d <<= 1)
#pragma unroll
      for (int i = 0; i < SROW * 4; ++i)
        rowmax[i] = fmaxf(rowmax[i], __shfl_xor(rowmax[i], d, 64));
    // emit retained slices against the (monotone, <= global-max) threshold
#pragma unroll
    for (int u = 0; u < GRP; ++u) {
      const int keyg = key0 + (gi + u) * 16 + ln;
#pragma unroll
      for (int s = 0; s < SROW; ++s)
#pragma unroll
        for (int r = 0; r < 4; ++r)
          if (acc[u][s][r] >= rowmax[s * 4 + r] - EMIT_MARGIN) {
            int q = qt * QT + s * 16 + g * 4 + r;
            int slot = atomicAdd(&mycnt[q], 1);
            if (slot < cap)
              cand[((size_t)net * NQ + q) * cap + slot] = pack16(keyg, acc[u][s][r]);
          }
    }
  }
}

// ------------------------------- refine ------------------------------------
// one block (256 thr) per (query, net).  Global candidate max from STORED
// fp16 scores; filter to survivors (>= max - SEL_MARGIN); exact fp32 scores
// for survivors only; exact softmax + PV.  Deterministic compaction order.
__global__ __launch_bounds__(256)
void refine_kernel(const float* __restrict__ qcur, const float* __restrict__ emb,
                   int* __restrict__ cnt, const unsigned* __restrict__ cand,
                   float* __restrict__ qnext, int cap) {
  const int q = blockIdx.x, net = blockIdx.y;
  const int tid = threadIdx.x, lane = tid & 63, w = tid >> 6;
  const int slot = net * NQ + q;
  __shared__ float qv[EDIM];
  __shared__ float osh[EDIM];
  __shared__ unsigned pr[MAXCAP];
  __shared__ unsigned surv[4][64];
  __shared__ unsigned list[256];
  __shared__ float exsc[256];
  __shared__ int scnt[4];
  __shared__ float red[8];

  const int ntot = cnt[slot];
  const int n = ntot < cap ? ntot : cap;
  if (tid < EDIM) qv[tid] = 2.0f * qcur[(size_t)slot * EDIM + tid];
  for (int j = tid; j < n; j += 256) pr[j] = cand[(size_t)slot * cap + j];
  __syncthreads();

  if (ntot <= cap) {
    // ---- global max over stored fp16 scores (no memory gather) ----
    float mx = -3.4e38f;
    for (int j = tid; j < n; j += 256) mx = fmaxf(mx, dec16(pr[j]));
#pragma unroll
    for (int d = 32; d; d >>= 1) mx = fmaxf(mx, __shfl_xor(mx, d, 64));
    if (lane == 0) red[w] = mx;
    __syncthreads();
    mx = fmaxf(fmaxf(red[0], red[1]), fmaxf(red[2], red[3]));
    const float th = mx - SEL_MARGIN;

    // ---- deterministic wave-striped compaction of survivors ----
    const int n4 = (n + 3) >> 2;
    const int lo = w * n4;
    const int hi = min(lo + n4, n);
    int c = 0;  // wave-uniform running count
    for (int base = lo; base < hi; base += 64) {
      const int j = base + lane;
      const bool p = (j < hi) && (dec16(pr[j]) >= th);
      const unsigned long long mb = __ballot(p);
      const int pos = c + __popcll(mb & ((1ull << lane) - 1));
      if (p && pos < 64) surv[w][pos] = pr[j];
      c += (int)__popcll(mb);
    }
    if (lane == 0) scnt[w] = c < 64 ? c : 64;
    __syncthreads();
    const int o1 = scnt[0], o2 = o1 + scnt[1], o3 = o2 + scnt[2];
    const int m = o3 + scnt[3];
    const int offw = (w == 0) ? 0 : (w == 1 ? o1 : (w == 2 ? o2 : o3));
    if (lane < scnt[w]) list[offw + lane] = surv[w][lane];
    __syncthreads();

    // ---- exact fp32 scores for the m survivors ----
    for (int j = w; j < m; j += 4) {
      const int ki = (int)(list[j] >> 16);
      const float* kr = emb + ((size_t)net * NKEY + ki) * ESTR;
      float p2 = qv[2 * lane] * kr[2 * lane] + qv[2 * lane + 1] * kr[2 * lane + 1];
#pragma unroll
      for (int d = 32; d; d >>= 1) p2 += __shfl_xor(p2, d, 64);
      if (lane == 0) exsc[j] = p2;
    }
    __syncthreads();
    if (w == 0) {
      float em = -3.4e38f;
      for (int j = lane; j < m; j += 64) em = fmaxf(em, exsc[j]);
#pragma unroll
      for (int d = 32; d; d >>= 1) em = fmaxf(em, __shfl_xor(em, d, 64));
      if (lane == 0) red[4] = em;
    }
    __syncthreads();
    const float em = red[4];
    for (int j = tid; j < m; j += 256) exsc[j] = expf(exsc[j] - em);
    __syncthreads();
    if (w == 0) {
      float l = 0.f;
      for (int j = lane; j < m; j += 64) l += exsc[j];
#pragma unroll
      for (int d = 32; d; d >>= 1) l += __shfl_xor(l, d, 64);
      if (lane == 0) red[5] = l;
    }
    __syncthreads();
    // ---- exact PV over survivors ----
    const float inv = 1.0f / red[5];
    const int e = tid & 127, hf = tid >> 7;
    float acc = 0.f;
    for (int j = hf; j < m; j += 2)
      acc += exsc[j] * emb[((size_t)net * NKEY + (int)(list[j] >> 16)) * ESTR + e];
    if (hf) osh[e] = acc;
    __syncthreads();
    if (!hf) qnext[(size_t)slot * EDIM + e] = (acc + osh[e]) * inv;
  } else {
    // ---- exact full-scan fallback (overflow only; never expected) ----
    float mm = -3.4e38f;
    for (int j = w; j < NKEY; j += 4) {
      const float* kr = emb + ((size_t)net * NKEY + j) * ESTR;
      float p = qv[2 * lane] * kr[2 * lane] + qv[2 * lane + 1] * kr[2 * lane + 1];
#pragma unroll
      for (int d = 32; d; d >>= 1) p += __shfl_xor(p, d, 64);
      mm = fmaxf(mm, p);
    }
    if (lane == 0) red[w] = mm;
    __syncthreads();
    mm = fmaxf(fmaxf(red[0], red[1]), fmaxf(red[2], red[3]));
    if (tid < EDIM) osh[tid] = 0.f;
    if (tid == 0) red[4] = 0.f;
    __syncthreads();
    float lpart = 0.f;
    for (int j = w; j < NKEY; j += 4) {
      const float* kr = emb + ((size_t)net * NKEY + j) * ESTR;
      float p = qv[2 * lane] * kr[2 * lane] + qv[2 * lane + 1] * kr[2 * lane + 1];
#pragma unroll
      for (int d = 32; d; d >>= 1) p += __shfl_xor(p, d, 64);
      float ee = expf(p - mm);
      if (lane == 0) lpart += ee;
      atomicAdd(&osh[2 * lane], ee * kr[2 * lane]);
      atomicAdd(&osh[2 * lane + 1], ee * kr[2 * lane + 1]);
    }
    if (lane == 0) atomicAdd(&red[4], lpart);
    __syncthreads();
    if (tid < EDIM) qnext[(size_t)slot * EDIM + tid] = osh[tid] / red[4];
  }
  __syncthreads();
  if (tid == 0) cnt[slot] = 0;  // ready for next step's scan
}

// ------------------------------- head --------------------------------------
__global__ __launch_bounds__(64)
void head_kernel(const float* __restrict__ qf, const float* __restrict__ Wl,
                 const float* __restrict__ bl, float* __restrict__ out) {
  const int b = blockIdx.x, lane = threadIdx.x;
  float acc[10];
#pragma unroll
  for (int c = 0; c < 10; ++c) acc[c] = 0.f;
  for (int t = lane; t < NNET * EDIM; t += 64) {
    float z = qf[((size_t)(t >> 7) * NQ + b) * EDIM + (t & 127)];
    z = fmaxf(z, 0.f);
    const float* wr = Wl + t * 10;
#pragma unroll
    for (int c = 0; c < 10; ++c) acc[c] += z * wr[c];
  }
#pragma unroll
  for (int d = 32; d; d >>= 1)
#pragma unroll
    for (int c = 0; c < 10; ++c) acc[c] += __shfl_xor(acc[c], d, 64);
  if (lane == 0) {
    float lg[10], mxv = -3.4e38f;
#pragma unroll
    for (int c = 0; c < 10; ++c) {
      lg[c] = acc[c] + bl[c];
      mxv = fmaxf(mxv, lg[c]);
    }
    float s = 0.f;
#pragma unroll
    for (int c = 0; c < 10; ++c) s += expf(lg[c] - mxv);
    float lse = mxv + logf(s);
#pragma unroll
    for (int c = 0; c < 10; ++c) out[b * 10 + c] = lg[c] - lse;
  }
}

// ------------------------------- launch ------------------------------------
extern "C" void kernel_launch(void* const* d_in, const int* in_sizes, int n_in,
                              void* d_out, int out_size, void* d_ws, size_t ws_size,
                              hipStream_t stream) {
  (void)in_sizes; (void)n_in; (void)out_size;
  const float* x   = (const float*)d_in[0];
  const float* emb = (const float*)d_in[1];
  const float* We  = (const float*)d_in[2];
  const float* be  = (const float*)d_in[3];
  const float* Wl  = (const float*)d_in[4];
  const float* bl  = (const float*)d_in[5];
  float* out = (float*)d_out;

  char* p = (char*)d_ws;
  float* q0 = (float*)p; p += (size_t)NNET * NQ * EDIM * 4;
  float* q1 = (float*)p; p += (size_t)NNET * NQ * EDIM * 4;
  int* cnt  = (int*)p;   p += (size_t)NNET * NQ * sizeof(int);
  size_t base = (size_t)(p - (char*)d_ws);
  int cap = MAXCAP;
  while (cap > 64 && base + (size_t)NNET * NQ * cap * 4 > ws_size) cap >>= 1;
  unsigned* cand = (unsigned*)p; p += (size_t)NNET * NQ * cap * 4;
  _Float16* kh = (_Float16*)p;
  const bool f16k =
      ((size_t)(p - (char*)d_ws) + (size_t)NNET * NKEY * EDIM * 2) <= ws_size;

  enc_kernel<<<dim3(NQ), dim3(128), 0, stream>>>(x, We, be, q0, cnt);
  if (f16k)
    keyprep_kernel<<<dim3(4096), dim3(256), 0, stream>>>(emb, kh);

  float* qa = q0;
  float* qb = q1;
  for (int step = 0; step < 4; ++step) {
    if (f16k)
      scan_kernel<true><<<dim3(NNET * NCHUNK, NQ / QT), dim3(SCAN_WAVES * 64), 0, stream>>>(
          qa, emb, kh, cnt, cand, cap);
    else
      scan_kernel<false><<<dim3(NNET * NCHUNK, NQ / QT), dim3(SCAN_WAVES * 64), 0, stream>>>(
          qa, emb, (const _Float16*)nullptr, cnt, cand, cap);
    refine_kernel<<<dim3(NQ, NNET), dim3(256), 0, stream>>>(qa, emb, cnt, cand, qb, cap);
    float* t = qa; qa = qb; qb = t;
  }
  head_kernel<<<dim3(NQ), dim3(64), 0, stream>>>(qa, Wl, bl, out);
}